// Round 2
// baseline (364.339 us; speedup 1.0000x reference)
//
#include <hip/hip_runtime.h>
#include <hip/hip_bf16.h>
#include <math.h>

#define B_  16
#define C_  256
#define T_  4096
#define K_  5

typedef __attribute__((ext_vector_type(4))) float floatx4;
typedef __attribute__((ext_vector_type(8))) short short8;

// ALL tensors f32. CORRECTNESS CONTRACT (verified R7, absmax 0.03125):
//  - offset conv for the 64 MAIN t of each tile MUST be bit-exact vs the
//    numpy golden: per-tap sequential channel sums (c ascending), separate
//    rounded mul+add (no FMA), taps combined ((d0+d1)+d2), bias last, then
//    pos = f32(t+k-2)+off in one add. Exact-integer pos => both weights 0.
//  - HALO columns (t0-1, t0+64) feed ONLY the recovery conv (smooth in pos,
//    bf16-rounded anyway) -> relaxed order/FMA is safe there. Clip-induced
//    integer pos gives weights==0 identically in any implementation.
//  - modulator conv / sigmoid are continuous: any precision/order OK.
//  - recovery may use bf16 MFMA (measured absmax 0.031 << 0.2475 threshold).

// ---------------- ws layout (bytes) — total 232448 ----------------
// 0       wk1   f32 [3][256][10]   30720  (tap-major; f 0..4 offset, 5..9 mod)
// 30720   diagw f32 [256][5]       5120
// 35840   w_r   bf16 [(d*8+m)*8+ch][512]  196608  (A-frags, wave-coalesced)

__global__ __launch_bounds__(256) void k0_setup(
    const float* __restrict__ ow, const float* __restrict__ mw,
    const float* __restrict__ wt, const float* __restrict__ r1w,
    float* __restrict__ wk1, float* __restrict__ diagw,
    __hip_bfloat16* __restrict__ w_r)
{
    int idx = blockIdx.x * 256 + threadIdx.x;
    if (idx < 98304) {
        int blk = idx >> 9;          // 0..191
        int r   = idx & 511;
        int ln  = r >> 5;
        int cc  = r & 31;
        int ch  = blk & 7;
        int dm  = blk >> 3;          // 0..23
        int m   = dm & 7;
        int d   = dm >> 3;           // 0..2
        int o   = m * 16 + ln;
        int c   = ch * 32 + cc;
        w_r[idx] = __float2bfloat16(r1w[((size_t)o * 256 + c) * 3 + d]);
    }
    if (idx < 7680) {
        int d = idx / 2560; int rem = idx - d * 2560; int c = rem / 10; int f = rem - c * 10;
        wk1[idx] = (f < 5) ? ow[(f * C_ + c) * 3 + d] : mw[((f - 5) * C_ + c) * 3 + d];
    }
    if (idx < 1280) {
        int c = idx / 5; int k = idx - c * 5;
        diagw[idx] = wt[((size_t)c * C_ + c) * K_ + k];
    }
}

// Fused kernel: 64-t tile, grid (64,16) = 1024 blocks, 256 threads,
// LDS 40.1 KB -> 4 blocks/CU.
//  phase A : waves 0-2 = bit-exact tap-split conv (16-deep x prefetch);
//            wave 3   = halo conv for t0-1 / t0+64 (channel-split, relaxed)
//  combine : 64 threads, bit-exact tap merge -> pos/floor/ceil/weights
//  phase B : 4 waves x 64-c groups; 2-row pipelined gather+deform;
//            writes f32 dout (mandatory) + bf16 LDS tile [66][264]
//  phase C : k3's MFMA (A-frags from L2 with 1-group register prefetch,
//            B-frags from LDS) + relu/rp2 epilogue -> rec
__global__ __launch_bounds__(256) void k_all(
    const float* __restrict__ x,
    const float* __restrict__ wk1,
    const float* __restrict__ ob, const float* __restrict__ mb,
    const float* __restrict__ diagw,
    const __hip_bfloat16* __restrict__ w_r,
    const float* __restrict__ rp1b, const float* __restrict__ rp2w,
    const float* __restrict__ rp2b,
    float* __restrict__ dout, float* __restrict__ rec)
{
    __shared__ __align__(16) short sdef[66 * 264];   // 34848 B; rows t0-1..t0+64
    __shared__ int   spf[K_][64];
    __shared__ int   spc[K_][64];
    __shared__ float swa[K_][64];
    __shared__ float swb[K_][64];
    __shared__ int   hpf[2][K_], hpc[2][K_];
    __shared__ float hwa[2][K_], hwb[2][K_];

    // staps/smod union with sdef: live only phase A -> combine; sdef rows are
    // written in phase B (after combine). [3][5][64] f32 each = 7680 B < 34848.
    float* staps = (float*)sdef;
    float* smod  = (float*)sdef + 960;

    const int t0  = blockIdx.x * 64;
    const int b   = blockIdx.y;
    const int tid = threadIdx.x;
    const int tl  = tid & 63;
    const int wv  = tid >> 6;
    const int t   = t0 + tl;

    // ================= phase A =================
    if (wv < 3) {
        const int wvu = __builtin_amdgcn_readfirstlane(wv);
        const int dd  = wvu - 1;                       // tap offset -1/0/+1
        const bool inb = ((unsigned)(t + dd) < (unsigned)T_);
        const float* xp = x + (size_t)b * C_ * T_ + t + (inb ? dd : 0);
        const float* wbase = wk1 + wvu * 2560;         // wave-uniform -> s_load
        float so0=0.f, so1=0.f, so2=0.f, so3=0.f, so4=0.f;   // strict chains
        float am0=0.f, am1=0.f, am2=0.f, am3=0.f, am4=0.f;   // mod partials
        float pv[16];
#pragma unroll
        for (int i = 0; i < 16; ++i) pv[i] = xp[(size_t)i * T_];
        for (int c16 = 0; c16 < 256; c16 += 16) {
            float cv[16];
#pragma unroll
            for (int i = 0; i < 16; ++i) cv[i] = pv[i];
            if (c16 + 16 < 256) {                      // prefetch next 16 channels
                const float* xq = xp + (size_t)(c16 + 16) * T_;
#pragma unroll
                for (int i = 0; i < 16; ++i) pv[i] = xq[(size_t)i * T_];
            }
#pragma unroll
            for (int i = 0; i < 16; ++i) {
                const float v = inb ? cv[i] : 0.f;     // exact zero-pad
                const float* wr_ = wbase + (c16 + i) * 10;
                {
#pragma clang fp contract(off)
                    // strict IEEE f32, c-ascending, separate rounded mul+add
                    float p0 = wr_[0] * v; so0 = so0 + p0;
                    float p1 = wr_[1] * v; so1 = so1 + p1;
                    float p2 = wr_[2] * v; so2 = so2 + p2;
                    float p3 = wr_[3] * v; so3 = so3 + p3;
                    float p4 = wr_[4] * v; so4 = so4 + p4;
                }
                am0 = fmaf(wr_[5], v, am0);
                am1 = fmaf(wr_[6], v, am1);
                am2 = fmaf(wr_[7], v, am2);
                am3 = fmaf(wr_[8], v, am3);
                am4 = fmaf(wr_[9], v, am4);
            }
        }
        staps[(wvu * 5 + 0) * 64 + tl] = so0;
        staps[(wvu * 5 + 1) * 64 + tl] = so1;
        staps[(wvu * 5 + 2) * 64 + tl] = so2;
        staps[(wvu * 5 + 3) * 64 + tl] = so3;
        staps[(wvu * 5 + 4) * 64 + tl] = so4;
        smod[(wvu * 5 + 0) * 64 + tl]  = am0;
        smod[(wvu * 5 + 1) * 64 + tl]  = am1;
        smod[(wvu * 5 + 2) * 64 + tl]  = am2;
        smod[(wvu * 5 + 3) * 64 + tl]  = am3;
        smod[(wvu * 5 + 4) * 64 + tl]  = am4;
    } else {
        // ---- halo conv (relaxed path; feeds recovery only) ----
        const int th = tl >> 5;                        // 0: t0-1, 1: t0+64
        const int cl = tl & 31;                        // 8 channels per lane
        const int tg = t0 - 1 + th * 65;
        const bool thin = ((unsigned)tg < (unsigned)T_);
        float ho[5] = {0.f,0.f,0.f,0.f,0.f};
        float hm[5] = {0.f,0.f,0.f,0.f,0.f};
        if (thin) {
            const float* xb = x + (size_t)b * C_ * T_ + tg;
            for (int cc = 0; cc < 8; ++cc) {
                const int c = cl * 8 + cc;
                const float* xr = xb + (size_t)c * T_;
                const float x0 = (tg >= 1)      ? xr[-1] : 0.f;
                const float x1 = xr[0];
                const float x2 = (tg < T_ - 1)  ? xr[1]  : 0.f;
                const float* w0 = wk1 + c * 10;
                const float* w1 = wk1 + 2560 + c * 10;
                const float* w2 = wk1 + 5120 + c * 10;
#pragma unroll
                for (int f = 0; f < 5; ++f) {
                    ho[f] += w0[f] * x0 + w1[f] * x1 + w2[f] * x2;
                    hm[f] += w0[5 + f] * x0 + w1[5 + f] * x1 + w2[5 + f] * x2;
                }
            }
        }
#pragma unroll
        for (int f = 0; f < 5; ++f) {
#pragma unroll
            for (int mk = 1; mk <= 16; mk <<= 1) {
                ho[f] += __shfl_xor(ho[f], mk);
                hm[f] += __shfl_xor(hm[f], mk);
            }
        }
        if (cl < 5) {
            const int k = cl;
            float offv = ho[k] + ob[k];
            float modv = hm[k] + mb[k];
            float sig  = 1.f / (1.f + expf(-modv));
            float pos  = (float)(tg + k - 2) + offv;
            pos = fminf(fmaxf(pos, 0.f), 4095.f);
            float pf = floorf(pos), pc = ceilf(pos);
            hpf[th][k] = (int)pf;
            hpc[th][k] = (int)pc;
            hwa[th][k] = thin ? (pc - pos) * sig : 0.f;
            hwb[th][k] = thin ? (pos - pf) * sig : 0.f;
        }
    }
    __syncthreads();

    // ================= combine (bit-exact) =================
    if (tid < 64) {
#pragma clang fp contract(off)
#pragma unroll
        for (int k = 0; k < K_; ++k) {
            float offv = ((staps[k * 64 + tl] + staps[(5 + k) * 64 + tl])
                          + staps[(10 + k) * 64 + tl]) + ob[k];
            float modv = ((smod[k * 64 + tl] + smod[(5 + k) * 64 + tl])
                          + smod[(10 + k) * 64 + tl]) + mb[k];
            float sig  = 1.f / (1.f + expf(-modv));
            float pos  = (float)(t + k - 2) + offv;   // single f32 add
            pos = fminf(fmaxf(pos, 0.f), 4095.f);
            float pf = floorf(pos), pc = ceilf(pos);
            spf[k][tl] = (int)pf;
            spc[k][tl] = (int)pc;
            swa[k][tl] = (pc - pos) * sig;
            swb[k][tl] = (pos - pf) * sig;
        }
    }
    __syncthreads();

    // ================= phase B =================
    const int cgU = __builtin_amdgcn_readfirstlane(wv);   // wave-uniform
    {
        int   pfk[K_], pck[K_];
        float ak[K_], bk[K_];
#pragma unroll
        for (int k = 0; k < K_; ++k) {
            pfk[k] = spf[k][tl]; pck[k] = spc[k][tl];
            ak[k]  = swa[k][tl]; bk[k]  = swb[k][tl];
        }
        const float* xr  = x    + (size_t)(b * C_ + cgU * 64) * T_;
        float*       dp  = dout + (size_t)(b * C_ + cgU * 64) * T_ + t;
        const float* dwp = diagw + cgU * 320;
        float vfA[K_], vcA[K_], vfB[K_], vcB[K_];
#pragma unroll
        for (int k = 0; k < K_; ++k) {
            vfA[k] = xr[pfk[k]];              vcA[k] = xr[pck[k]];
            vfB[k] = xr[T_ + pfk[k]];         vcB[k] = xr[T_ + pck[k]];
        }
        for (int j = 0; j < 64; j += 2) {
            float nfA[K_], ncA[K_], nfB[K_], ncB[K_];
            if (j < 62) {                     // 2-row lookahead
                const float* xa = xr + (size_t)(j + 2) * T_;
                const float* xb2 = xr + (size_t)(j + 3) * T_;
#pragma unroll
                for (int k = 0; k < K_; ++k) {
                    nfA[k] = xa[pfk[k]];  ncA[k] = xa[pck[k]];
                    nfB[k] = xb2[pfk[k]]; ncB[k] = xb2[pck[k]];
                }
            }
            float a0 = 0.f, a1 = 0.f;
#pragma unroll
            for (int k = 0; k < K_; ++k) {
                a0 += dwp[j * 5 + k]       * (vfA[k] * ak[k] + vcA[k] * bk[k]);
                a1 += dwp[(j + 1) * 5 + k] * (vfB[k] * ak[k] + vcB[k] * bk[k]);
            }
            dp[(size_t)j * T_]       = a0;
            dp[(size_t)(j + 1) * T_] = a1;
            __hip_bfloat16 h0 = __float2bfloat16(a0);
            __hip_bfloat16 h1 = __float2bfloat16(a1);
            unsigned pk2 = (unsigned)*(unsigned short*)&h0
                         | ((unsigned)*(unsigned short*)&h1 << 16);
            *(unsigned*)&sdef[(tl + 1) * 264 + cgU * 64 + j] = pk2;  // dword-aligned
            if (j < 62) {
#pragma unroll
                for (int k = 0; k < K_; ++k) {
                    vfA[k] = nfA[k]; vcA[k] = ncA[k];
                    vfB[k] = nfB[k]; vcB[k] = ncB[k];
                }
            }
        }
        // halo deformed rows (0 and 65): lane = channel within this c-group
        {
            const int c = cgU * 64 + tl;
            const float* xrc = x + (size_t)(b * C_ + c) * T_;
            const float* dwc = diagw + c * 5;
#pragma unroll
            for (int th = 0; th < 2; ++th) {
                float a2 = 0.f;
#pragma unroll
                for (int k = 0; k < K_; ++k)
                    a2 += dwc[k] * (xrc[hpf[th][k]] * hwa[th][k]
                                  + xrc[hpc[th][k]] * hwb[th][k]);
                __hip_bfloat16 h = __float2bfloat16(a2);
                sdef[(th * 65) * 264 + c] = *(short*)&h;
            }
        }
    }
    __syncthreads();

    // ================= phase C: recovery MFMA =================
    {
        const int qd = tl >> 4;
        const int ln = tl & 15;
        const short* wsrc = (const short*)w_r;
        floatx4 acc[8];
#pragma unroll
        for (int m = 0; m < 8; ++m) acc[m] = (floatx4){0.f, 0.f, 0.f, 0.f};

        short8 afA[8], afB[8];
#pragma unroll
        for (int m = 0; m < 8; ++m)      // g=0: d=0, ch=0
            afA[m] = *(const short8*)(wsrc + (size_t)(m * 8) * 512 + ln * 32 + qd * 8);
#pragma unroll
        for (int g = 0; g < 24; ++g) {   // g = ch*3 + d
            const int ch = g / 3, d = g - ch * 3;
            if (g < 23) {                // prefetch next frag group (alt buffer)
                const int g2 = g + 1;
                const int ch2 = g2 / 3, d2 = g2 - ch2 * 3;
                if (g & 1) {
#pragma unroll
                    for (int m = 0; m < 8; ++m)
                        afA[m] = *(const short8*)(wsrc
                            + (size_t)(((d2 * 8 + m) * 8 + ch2) * 512) + ln * 32 + qd * 8);
                } else {
#pragma unroll
                    for (int m = 0; m < 8; ++m)
                        afB[m] = *(const short8*)(wsrc
                            + (size_t)(((d2 * 8 + m) * 8 + ch2) * 512) + ln * 32 + qd * 8);
                }
            }
            short8 bfr = *(const short8*)&sdef[(cgU * 16 + ln + d) * 264 + ch * 32 + qd * 8];
            if (g & 1) {
#pragma unroll
                for (int m = 0; m < 8; ++m)
                    acc[m] = __builtin_amdgcn_mfma_f32_16x16x32_bf16(afB[m], bfr, acc[m], 0, 0, 0);
            } else {
#pragma unroll
                for (int m = 0; m < 8; ++m)
                    acc[m] = __builtin_amdgcn_mfma_f32_16x16x32_bf16(afA[m], bfr, acc[m], 0, 0, 0);
            }
        }

        // epilogue (C/D layout: col=ln -> t, row=qd*4+reg -> o)
        float rv = 0.f;
#pragma unroll
        for (int m = 0; m < 8; ++m)
#pragma unroll
            for (int r = 0; r < 4; ++r) {
                int o = m * 16 + qd * 4 + r;
                float h = acc[m][r] + rp1b[o];
                h = h > 0.f ? h : 0.f;
                rv += rp2w[o] * h;
            }
        rv += __shfl_xor(rv, 16);
        rv += __shfl_xor(rv, 32);
        if (qd == 0)
            rec[b * T_ + t0 + cgU * 16 + ln] = rv + rp2b[0];
    }
}

extern "C" void kernel_launch(void* const* d_in, const int* in_sizes, int n_in,
                              void* d_out, int out_size, void* d_ws, size_t ws_size,
                              hipStream_t stream) {
    const float* x   = (const float*)d_in[0];
    const float* ow  = (const float*)d_in[1];
    const float* ob  = (const float*)d_in[2];
    const float* mw  = (const float*)d_in[3];
    const float* mb  = (const float*)d_in[4];
    const float* wt  = (const float*)d_in[5];
    const float* r1w = (const float*)d_in[6];
    const float* r1b = (const float*)d_in[7];
    const float* r2w = (const float*)d_in[8];
    const float* r2b = (const float*)d_in[9];

    char* ws = (char*)d_ws;
    float*          wk1   = (float*)(ws + 0);
    float*          diagw = (float*)(ws + 30720);
    __hip_bfloat16* w_r   = (__hip_bfloat16*)(ws + 35840);

    float* dout = (float*)d_out;
    float* rec  = (float*)d_out + (size_t)B_ * C_ * T_;

    k0_setup<<<384, 256, 0, stream>>>(ow, mw, wt, r1w, wk1, diagw, w_r);
    k_all<<<dim3(T_ / 64, B_), 256, 0, stream>>>(x, wk1, ob, mb, diagw, w_r,
                                                 r1b, r2w, r2b, dout, rec);
}

// Round 3
// 282.633 us; speedup vs baseline: 1.2891x; 1.2891x over previous
//
#include <hip/hip_runtime.h>
#include <hip/hip_bf16.h>
#include <math.h>

#define B_  16
#define C_  256
#define T_  4096
#define K_  5

typedef __attribute__((ext_vector_type(4))) float floatx4;
typedef __attribute__((ext_vector_type(8))) short short8;

// ALL tensors f32. CORRECTNESS CONTRACT (verified R7, absmax 0.03125):
//  - offset conv MUST be bit-exact vs the numpy golden: per-tap sequential
//    channel sums (c ascending 0..255), separate rounded mul+add (no FMA),
//    taps combined ((d0+d1)+d2), bias last, then pos = f32(t+k-2)+off in one
//    add. Exact-integer pos => both weights 0 (the discontinuity events).
//    Tap-split across waves preserves bit-exactness (each (d,f) chain keeps
//    its full-length c-order). 3-buffer prefetch rotation below processes
//    groups 0..15 strictly in order -> unchanged summation order.
//  - modulator conv / sigmoid are continuous: any precision/order OK.
//  - k3 may use bf16 MFMA (measured absmax 0.031 << thresholds).

// ---------------- ws layout (bytes) — total 232448 ----------------
// 0       wk1   f32 [3][256][10]   30720   (tap-major; f 0..4 offset, 5..9 mod)
// 30720   diagw f32 [256][5]       5120
// 35840   w_r   bf16 [3][128][256] 196608  (rp1_w repacked for k3 LDS staging)

__global__ __launch_bounds__(256) void k0_setup(
    const float* __restrict__ ow, const float* __restrict__ mw,
    const float* __restrict__ wt, const float* __restrict__ r1w,
    float* __restrict__ wk1, float* __restrict__ diagw,
    __hip_bfloat16* __restrict__ w_r)
{
    int idx = blockIdx.x * 256 + threadIdx.x;
    if (idx < 98304) {
        // rp1_w[(o*256+c)*3+d] -> w_r[(d*128+o)*256+c]
        int o = idx / 768; int rem = idx - o * 768; int c = rem / 3; int d = rem - c * 3;
        w_r[(size_t)(d * 128 + o) * 256 + c] = __float2bfloat16(r1w[idx]);
    }
    if (idx < 7680) {
        // wk1[(d*256 + c)*10 + f]: contiguous 40B per (d,c) -> one s_load group
        int d = idx / 2560; int rem = idx - d * 2560; int c = rem / 10; int f = rem - c * 10;
        wk1[idx] = (f < 5) ? ow[(f * C_ + c) * 3 + d] : mw[((f - 5) * C_ + c) * 3 + d];
    }
    if (idx < 1280) {
        int c = idx / 5; int k = idx - c * 5;
        diagw[idx] = wt[((size_t)c * C_ + c) * K_ + k];
    }
}

// phase-A helpers: 16-channel group load / process (strict order preserved)
#define LOADG(BUF, GG) do { \
    _Pragma("unroll") \
    for (int i_ = 0; i_ < 16; ++i_) \
        BUF[i_] = xp[(size_t)((GG) * 16 + i_) * T_]; \
} while (0)

#define PROCG(BUF, GG) do { \
    _Pragma("unroll") \
    for (int i_ = 0; i_ < 16; ++i_) { \
        const float v_ = inb ? BUF[i_] : 0.f; \
        const float* wr_ = wbase + ((GG) * 16 + i_) * 10; \
        { \
            _Pragma("clang fp contract(off)") \
            float q0 = wr_[0] * v_; so0 = so0 + q0; \
            float q1 = wr_[1] * v_; so1 = so1 + q1; \
            float q2 = wr_[2] * v_; so2 = so2 + q2; \
            float q3 = wr_[3] * v_; so3 = so3 + q3; \
            float q4 = wr_[4] * v_; so4 = so4 + q4; \
        } \
        am0 = fmaf(wr_[5], v_, am0); \
        am1 = fmaf(wr_[6], v_, am1); \
        am2 = fmaf(wr_[7], v_, am2); \
        am3 = fmaf(wr_[8], v_, am3); \
        am4 = fmaf(wr_[9], v_, am4); \
    } \
} while (0)

// K12 v4: 64-t tile, 256 threads, grid (64,16) = 1024 blocks.
// Phase A: tap-split across waves 0..2; 3-buffer (2-group, ~960cy) prefetch.
// Combine: 64 threads, bit-exact tap merge. Phase B: 4 waves x 64-c groups,
// 2-row software-pipelined gather+deform.
__global__ __launch_bounds__(256) void k12_fused(
    const float* __restrict__ x,
    const float* __restrict__ wk1,
    const float* __restrict__ ob, const float* __restrict__ mb,
    const float* __restrict__ diagw,
    float* __restrict__ dout)
{
    __shared__ float staps[3][K_][64];
    __shared__ float smod[3][K_][64];
    __shared__ int   spf[K_][64];
    __shared__ int   spc[K_][64];
    __shared__ float swa[K_][64];
    __shared__ float swb[K_][64];
    const int t0  = blockIdx.x * 64;
    const int b   = blockIdx.y;
    const int tid = threadIdx.x;
    const int tl  = tid & 63;
    const int wv  = tid >> 6;
    const int t   = t0 + tl;

    if (wv < 3) {
        const int wvu = __builtin_amdgcn_readfirstlane(wv);
        const int dd  = wvu - 1;                       // tap offset -1/0/+1
        const bool inb = ((unsigned)(t + dd) < (unsigned)T_);
        const float* xp = x + (size_t)b * C_ * T_ + t + (inb ? dd : 0);
        const float* wbase = wk1 + wvu * 2560;         // wave-uniform -> s_load
        float so0=0.f, so1=0.f, so2=0.f, so3=0.f, so4=0.f;   // strict chains
        float am0=0.f, am1=0.f, am2=0.f, am3=0.f, am4=0.f;   // mod partials
        float pA[16], pB[16], pC[16];
        LOADG(pA, 0); LOADG(pB, 1); LOADG(pC, 2);
#pragma unroll
        for (int g = 0; g < 16; g += 3) {
            PROCG(pA, g);
            if (g + 3 < 16) LOADG(pA, g + 3);
            if (g + 1 < 16) { PROCG(pB, g + 1); if (g + 4 < 16) LOADG(pB, g + 4); }
            if (g + 2 < 16) { PROCG(pC, g + 2); if (g + 5 < 16) LOADG(pC, g + 5); }
        }
        staps[wvu][0][tl] = so0; staps[wvu][1][tl] = so1; staps[wvu][2][tl] = so2;
        staps[wvu][3][tl] = so3; staps[wvu][4][tl] = so4;
        smod[wvu][0][tl]  = am0; smod[wvu][1][tl]  = am1; smod[wvu][2][tl]  = am2;
        smod[wvu][3][tl]  = am3; smod[wvu][4][tl]  = am4;
    }
    __syncthreads();

    if (tid < 64) {
#pragma clang fp contract(off)
#pragma unroll
        for (int k = 0; k < K_; ++k) {
            float offv = ((staps[0][k][tl] + staps[1][k][tl]) + staps[2][k][tl]) + ob[k];
            float modv = ((smod[0][k][tl] + smod[1][k][tl]) + smod[2][k][tl]) + mb[k];
            float sig  = 1.f / (1.f + expf(-modv));
            float pos  = (float)(t + k - 2) + offv;   // single f32 add
            pos = fminf(fmaxf(pos, 0.f), 4095.f);
            float pf = floorf(pos), pc = ceilf(pos);
            spf[k][tl] = (int)pf;
            spc[k][tl] = (int)pc;
            swa[k][tl] = (pc - pos) * sig;
            swb[k][tl] = (pos - pf) * sig;
        }
    }
    __syncthreads();

    // ---- phase B: deform gather; thread (cg, tl) covers c in [cg*64, cg*64+64) ----
    const int cgU = __builtin_amdgcn_readfirstlane(wv);   // wave-uniform
    int   pfk[K_], pck[K_];
    float ak[K_], bk[K_];
#pragma unroll
    for (int k = 0; k < K_; ++k) {
        pfk[k] = spf[k][tl]; pck[k] = spc[k][tl];
        ak[k]  = swa[k][tl]; bk[k]  = swb[k][tl];
    }
    const float* xr  = x    + (size_t)(b * C_ + cgU * 64) * T_;
    float*       dp  = dout + (size_t)(b * C_ + cgU * 64) * T_ + t;
    const float* dwp = diagw + cgU * 320;
    float vfA[K_], vcA[K_], vfB[K_], vcB[K_];
#pragma unroll
    for (int k = 0; k < K_; ++k) {
        vfA[k] = xr[pfk[k]];              vcA[k] = xr[pck[k]];
        vfB[k] = xr[T_ + pfk[k]];         vcB[k] = xr[T_ + pck[k]];
    }
    for (int j = 0; j < 64; j += 2) {
        float nfA[K_], ncA[K_], nfB[K_], ncB[K_];
        if (j < 62) {                     // 2-row lookahead
            const float* xa  = xr + (size_t)(j + 2) * T_;
            const float* xb2 = xr + (size_t)(j + 3) * T_;
#pragma unroll
            for (int k = 0; k < K_; ++k) {
                nfA[k] = xa[pfk[k]];  ncA[k] = xa[pck[k]];
                nfB[k] = xb2[pfk[k]]; ncB[k] = xb2[pck[k]];
            }
        }
        float a0 = 0.f, a1 = 0.f;
#pragma unroll
        for (int k = 0; k < K_; ++k) {
            a0 += dwp[j * 5 + k]       * (vfA[k] * ak[k] + vcA[k] * bk[k]);
            a1 += dwp[(j + 1) * 5 + k] * (vfB[k] * ak[k] + vcB[k] * bk[k]);
        }
        dp[(size_t)j * T_]       = a0;
        dp[(size_t)(j + 1) * T_] = a1;
        if (j < 62) {
#pragma unroll
            for (int k = 0; k < K_; ++k) {
                vfA[k] = nfA[k]; vcA[k] = ncA[k];
                vfB[k] = nfB[k]; vcB[k] = ncB[k];
            }
        }
    }
}

// K3 v2 (restored from round-0 baseline, ~48 us): 64-t tile, grid (64,16),
// LDS 36 KB -> 4 blocks/CU (16 waves/CU). Wave w = n-tile (16 t); 8 m-tiles
// of 16 o; K = 256c x 3taps. W staged in LDS per chunk (L2-resident source).
__global__ __launch_bounds__(256) void k3_rp(
    const float* __restrict__ ddef,              // f32 deformed [b][c][t] (d_out)
    const __hip_bfloat16* __restrict__ w_r,      // bf16 [3][128][256]
    const float* __restrict__ rp1b, const float* __restrict__ rp2w,
    const float* __restrict__ rp2b,
    float* __restrict__ rec)
{
    __shared__ __align__(16) short lw[3 * 128 * 40];  // [d][o][c stride 40] 30720 B
    __shared__ __align__(16) short ld[66 * 40];       // [j 66][c stride 40]   5280 B
    const int t0 = blockIdx.x * 64;
    const int b  = blockIdx.y;
    const int tid  = threadIdx.x;
    const int lane = tid & 63;
    const int w    = tid >> 6;      // wave id = n-tile
    const int qd   = lane >> 4;
    const int ln   = lane & 15;

    floatx4 acc[8];
#pragma unroll
    for (int m = 0; m < 8; ++m) acc[m] = (floatx4){0.f, 0.f, 0.f, 0.f};

    for (int ch = 0; ch < 8; ++ch) {
        int c0 = ch * 32;
        __syncthreads();
        // stage W chunk [3][128][32], 16B copies (6 per thread)
        for (int f = tid; f < 1536; f += 256) {
            int c8 = (f & 3) * 8;
            int o  = (f >> 2) & 127;
            int d  = f >> 9;
            *(int4*)&lw[(d * 128 + o) * 40 + c8] =
                *(const int4*)((const short*)w_r + (size_t)(d * 128 + o) * 256 + c0 + c8);
        }
        // stage D chunk transposed: ld[j][c], j -> global t0-1+j
        for (int f = tid; f < 32 * 66; f += 256) {
            int c = f / 66;
            int j = f - c * 66;
            int g = t0 - 1 + j;
            float v = (g >= 0 && g < T_) ? ddef[(size_t)(b * C_ + c0 + c) * T_ + g] : 0.f;
            __hip_bfloat16 h = __float2bfloat16(v);
            ld[j * 40 + c] = *(short*)&h;
        }
        __syncthreads();
#pragma unroll
        for (int d = 0; d < 3; ++d) {
            short8 bf = *(const short8*)&ld[(w * 16 + ln + d) * 40 + qd * 8];
#pragma unroll
            for (int m = 0; m < 8; ++m) {
                short8 af = *(const short8*)&lw[(d * 128 + m * 16 + ln) * 40 + qd * 8];
                acc[m] = __builtin_amdgcn_mfma_f32_16x16x32_bf16(af, bf, acc[m], 0, 0, 0);
            }
        }
    }

    // epilogue (C/D layout: col=ln -> t, row=qd*4+reg -> o)
    float rv = 0.f;
#pragma unroll
    for (int m = 0; m < 8; ++m)
#pragma unroll
        for (int r = 0; r < 4; ++r) {
            int o = m * 16 + qd * 4 + r;
            float h = acc[m][r] + rp1b[o];
            h = h > 0.f ? h : 0.f;
            rv += rp2w[o] * h;
        }
    rv += __shfl_xor(rv, 16);
    rv += __shfl_xor(rv, 32);
    if (qd == 0)
        rec[b * T_ + t0 + w * 16 + ln] = rv + rp2b[0];
}

extern "C" void kernel_launch(void* const* d_in, const int* in_sizes, int n_in,
                              void* d_out, int out_size, void* d_ws, size_t ws_size,
                              hipStream_t stream) {
    const float* x   = (const float*)d_in[0];
    const float* ow  = (const float*)d_in[1];
    const float* ob  = (const float*)d_in[2];
    const float* mw  = (const float*)d_in[3];
    const float* mb  = (const float*)d_in[4];
    const float* wt  = (const float*)d_in[5];
    const float* r1w = (const float*)d_in[6];
    const float* r1b = (const float*)d_in[7];
    const float* r2w = (const float*)d_in[8];
    const float* r2b = (const float*)d_in[9];

    char* ws = (char*)d_ws;
    float*          wk1   = (float*)(ws + 0);
    float*          diagw = (float*)(ws + 30720);
    __hip_bfloat16* w_r   = (__hip_bfloat16*)(ws + 35840);

    float* dout = (float*)d_out;
    float* rec  = (float*)d_out + (size_t)B_ * C_ * T_;

    k0_setup<<<384, 256, 0, stream>>>(ow, mw, wt, r1w, wk1, diagw, w_r);
    k12_fused<<<dim3(T_ / 64, B_), 256, 0, stream>>>(x, wk1, ob, mb, diagw, dout);
    k3_rp<<<dim3(T_ / 64, B_), 256, 0, stream>>>(dout, w_r, r1b, r2w, r2b, rec);
}